// Round 1
// baseline (548.113 us; speedup 1.0000x reference)
//
#include <hip/hip_runtime.h>

// Flash attention fwd, B=2 H=12 S=4096 D=64, fp32 in/out, bf16 MFMA compute.
// Round 0: correctness-first structure. 4 waves/block, 64 q-rows/block,
// KV tile = 64, K row-major + V transposed in LDS (both XOR-swizzled),
// P through wave-private LDS for D-layout -> A-layout conversion.

typedef float f32x4 __attribute__((ext_vector_type(4)));
typedef short short8 __attribute__((ext_vector_type(8)));
typedef __bf16 bf16x8 __attribute__((ext_vector_type(8)));

#define NB 2
#define NH 12
#define SEQ 4096
#define HD 64
#define QBLK 64
#define KVBLK 64
#define NT (SEQ / KVBLK)

__device__ __forceinline__ unsigned short f2bf(float x) {
    unsigned u = __builtin_bit_cast(unsigned, x);
    u += 0x7fffu + ((u >> 16) & 1u);   // round-to-nearest-even
    return (unsigned short)(u >> 16);
}

// byte offset into a row-major [R][64] bf16 tile (128B rows), bank-swizzled
__device__ __forceinline__ int swz(int row, int colByte) {
    return row * 128 + (colByte ^ ((row & 7) << 4));
}

__global__ __launch_bounds__(256, 4) void attn_kernel(
    const float* __restrict__ Qg, const float* __restrict__ Kg,
    const float* __restrict__ Vg, float* __restrict__ Og)
{
    __shared__ short Ksm[KVBLK * HD];      // [key][feat], swizzled
    __shared__ short Vsm[HD * KVBLK];      // [feat][key], swizzled (V^T)
    __shared__ short Psm[4 * 16 * KVBLK];  // per-wave P [q][key], swizzled

    const int tid = threadIdx.x;
    const int w  = tid >> 6;
    const int l  = tid & 63;
    const int lg = l >> 4;    // lane group 0..3
    const int ll = l & 15;    // lane low 0..15

    const int head = blockIdx.y;
    const size_t hoff = (size_t)head * SEQ * HD;
    const int qbase = blockIdx.x * QBLK + w * 16;

    // ---- Q fragments (A-layout: row=ll, k = lg*8 + j + 32*c), scale folded in
    short8 qf[2];
    {
        const float* qp = Qg + hoff + (size_t)(qbase + ll) * HD + lg * 8;
        #pragma unroll
        for (int c = 0; c < 2; ++c) {
            f32x4 a = *(const f32x4*)(qp + c * 32);
            f32x4 b = *(const f32x4*)(qp + c * 32 + 4);
            short8 t;
            #pragma unroll
            for (int j = 0; j < 4; ++j) {
                t[j]     = (short)f2bf(a[j] * 0.125f);
                t[j + 4] = (short)f2bf(b[j] * 0.125f);
            }
            qf[c] = t;
        }
    }

    float M[4], L[4];
    f32x4 o[4];
    const f32x4 zero = {0.f, 0.f, 0.f, 0.f};
    #pragma unroll
    for (int jj = 0; jj < 4; ++jj) { M[jj] = -1e30f; L[jj] = 0.f; }
    #pragma unroll
    for (int dt = 0; dt < 4; ++dt) o[dt] = zero;

    const int r0 = tid >> 3;          // staging row 0..31
    const int c0 = (tid & 7) * 8;     // staging feat start
    char* const Kb = (char*)Ksm;
    char* const Vb = (char*)Vsm;
    char* const Pb = (char*)Psm + w * (16 * KVBLK * 2);

    for (int t = 0; t < NT; ++t) {
        const int kv0 = t * KVBLK;
        __syncthreads();  // previous tile fully consumed
        // ---- stage K (row-major) and V^T, fp32 -> bf16
        #pragma unroll
        for (int half = 0; half < 2; ++half) {
            const int r = r0 + half * 32;
            const float* kp = Kg + hoff + (size_t)(kv0 + r) * HD + c0;
            f32x4 a = *(const f32x4*)kp;
            f32x4 b = *(const f32x4*)(kp + 4);
            short8 kv;
            #pragma unroll
            for (int j = 0; j < 4; ++j) {
                kv[j]     = (short)f2bf(a[j]);
                kv[j + 4] = (short)f2bf(b[j]);
            }
            *(short8*)(Kb + swz(r, c0 * 2)) = kv;

            const float* vp = Vg + hoff + (size_t)(kv0 + r) * HD + c0;
            f32x4 va = *(const f32x4*)vp;
            f32x4 vb2 = *(const f32x4*)(vp + 4);
            #pragma unroll
            for (int j = 0; j < 4; ++j) {
                *(short*)(Vb + swz(c0 + j,     r * 2)) = (short)f2bf(va[j]);
                *(short*)(Vb + swz(c0 + 4 + j, r * 2)) = (short)f2bf(vb2[j]);
            }
        }
        __syncthreads();

        // ---- QK^T: S[16 q][64 keys] in 4 col-tiles
        f32x4 sc[4];
        #pragma unroll
        for (int ct = 0; ct < 4; ++ct) {
            f32x4 acc = zero;
            #pragma unroll
            for (int c = 0; c < 2; ++c) {
                short8 kb = *(const short8*)(Kb + swz(ct * 16 + ll, (c * 32 + lg * 8) * 2));
                acc = __builtin_amdgcn_mfma_f32_16x16x32_bf16(
                    __builtin_bit_cast(bf16x8, qf[c]),
                    __builtin_bit_cast(bf16x8, kb), acc, 0, 0, 0);
            }
            sc[ct] = acc;
        }

        // ---- online softmax; row jj held by 16 lanes sharing lg
        #pragma unroll
        for (int jj = 0; jj < 4; ++jj) {
            float m = fmaxf(fmaxf(sc[0][jj], sc[1][jj]), fmaxf(sc[2][jj], sc[3][jj]));
            m = fmaxf(m, __shfl_xor(m, 1));
            m = fmaxf(m, __shfl_xor(m, 2));
            m = fmaxf(m, __shfl_xor(m, 4));
            m = fmaxf(m, __shfl_xor(m, 8));
            const float mn = fmaxf(M[jj], m);
            const float corr = __expf(M[jj] - mn);
            M[jj] = mn;
            float p0 = __expf(sc[0][jj] - mn);
            float p1 = __expf(sc[1][jj] - mn);
            float p2 = __expf(sc[2][jj] - mn);
            float p3 = __expf(sc[3][jj] - mn);
            sc[0][jj] = p0; sc[1][jj] = p1; sc[2][jj] = p2; sc[3][jj] = p3;
            float s = (p0 + p1) + (p2 + p3);
            s += __shfl_xor(s, 1);
            s += __shfl_xor(s, 2);
            s += __shfl_xor(s, 4);
            s += __shfl_xor(s, 8);
            L[jj] = L[jj] * corr + s;
            #pragma unroll
            for (int dt = 0; dt < 4; ++dt) o[dt][jj] *= corr;
        }

        // ---- P: D-layout regs -> wave-private LDS [q][key] (bf16)
        #pragma unroll
        for (int ct = 0; ct < 4; ++ct) {
            #pragma unroll
            for (int jj = 0; jj < 4; ++jj) {
                *(short*)(Pb + swz(lg * 4 + jj, (ct * 16 + ll) * 2)) =
                    (short)f2bf(sc[ct][jj]);
            }
        }

        // ---- PV: O += P(16x64) * V(64x64)
        #pragma unroll
        for (int kc = 0; kc < 2; ++kc) {
            short8 pa = *(const short8*)(Pb + swz(ll, (kc * 32 + lg * 8) * 2));
            #pragma unroll
            for (int dt = 0; dt < 4; ++dt) {
                short8 vbf = *(const short8*)(Vb + swz(dt * 16 + ll, (kc * 32 + lg * 8) * 2));
                o[dt] = __builtin_amdgcn_mfma_f32_16x16x32_bf16(
                    __builtin_bit_cast(bf16x8, pa),
                    __builtin_bit_cast(bf16x8, vbf), o[dt], 0, 0, 0);
            }
        }
    }

    // ---- epilogue: normalize and store fp32
    float* op = Og + hoff;
    #pragma unroll
    for (int jj = 0; jj < 4; ++jj) {
        const float inv = 1.0f / L[jj];
        const int q = qbase + lg * 4 + jj;
        #pragma unroll
        for (int dt = 0; dt < 4; ++dt)
            op[(size_t)q * HD + dt * 16 + ll] = o[dt][jj] * inv;
    }
}

extern "C" void kernel_launch(void* const* d_in, const int* in_sizes, int n_in,
                              void* d_out, int out_size, void* d_ws, size_t ws_size,
                              hipStream_t stream) {
    const float* Q = (const float*)d_in[0];
    const float* K = (const float*)d_in[1];
    const float* V = (const float*)d_in[2];
    float* O = (float*)d_out;
    dim3 grid(SEQ / QBLK, NB * NH);
    attn_kernel<<<grid, 256, 0, stream>>>(Q, K, V, O);
}

// Round 2
// 329.519 us; speedup vs baseline: 1.6634x; 1.6634x over previous
//
#include <hip/hip_runtime.h>

// Flash attention fwd, B=2 H=12 S=4096 D=64, fp32 in/out, bf16 MFMA compute.
// Round 2: pre-convert K (bf16, swizzled tiles) and V (transposed bf16,
// swizzled tiles) into d_ws; main kernel stages via global_load_lds(16B)
// with double-buffered 2-phase pipeline; XCD-aware block swizzle.

typedef float f32x4 __attribute__((ext_vector_type(4)));
typedef short short8 __attribute__((ext_vector_type(8)));
typedef __bf16 bf16x8 __attribute__((ext_vector_type(8)));

#define NB 2
#define NH 12
#define NHEADS (NB * NH)
#define SEQ 4096
#define HD 64
#define QBLK 64
#define KVBLK 64
#define NT (SEQ / KVBLK)
#define NQB (SEQ / QBLK)
#define TILE_BYTES (KVBLK * HD * 2)            // 8192 B per bf16 tile
#define WS_NEEDED ((size_t)NHEADS * SEQ * HD * 2 * 2)

__device__ __forceinline__ unsigned short f2bf(float x) {
    unsigned u = __builtin_bit_cast(unsigned, x);
    u += 0x7fffu + ((u >> 16) & 1u);   // round-to-nearest-even
    return (unsigned short)(u >> 16);
}

// byte offset into a row-major [R][64] bf16 tile (128B rows), bank-swizzled
__device__ __forceinline__ int swz(int row, int colByte) {
    return row * 128 + (colByte ^ ((row & 7) << 4));
}

// ---------------- pre-pass: K -> bf16 swizzled tiles ----------------
__global__ __launch_bounds__(256) void conv_k(const float* __restrict__ Kg,
                                              char* __restrict__ Kw) {
    const int g = blockIdx.x * 256 + threadIdx.x;   // one 8-element block
    const int e0 = g * 8;
    const int head = e0 >> 18;                      // SEQ*HD = 262144
    const int rem = e0 & (262144 - 1);
    const int row = rem >> 6;
    const int col = rem & 63;
    const int tile = row >> 6;
    const int r = row & 63;
    f32x4 a = *(const f32x4*)(Kg + (size_t)e0);
    f32x4 b = *(const f32x4*)(Kg + (size_t)e0 + 4);
    short8 t;
    #pragma unroll
    for (int j = 0; j < 4; ++j) {
        t[j]     = (short)f2bf(a[j]);
        t[j + 4] = (short)f2bf(b[j]);
    }
    *(short8*)(Kw + ((size_t)head * NT + tile) * TILE_BYTES + swz(r, col * 2)) = t;
}

// ---------- pre-pass: V -> V^T bf16 swizzled tiles (via LDS) ----------
__global__ __launch_bounds__(256) void conv_vt(const float* __restrict__ Vg,
                                               char* __restrict__ Vw) {
    __shared__ float tile[64][65];   // +1 pad: conflict-free column reads
    const int b = blockIdx.x;        // head * NT + t
    const int tid = threadIdx.x;
    const float* src = Vg + (size_t)b * (KVBLK * HD);
    const int r = tid >> 2;
    const int c = (tid & 3) * 16;
    f32x4 v[4];
    #pragma unroll
    for (int j = 0; j < 4; ++j) v[j] = *(const f32x4*)(src + r * 64 + c + j * 4);
    #pragma unroll
    for (int j = 0; j < 16; ++j) tile[r][c + j] = v[j >> 2][j & 3];
    __syncthreads();
    const int f = r;                 // output feature row
    const int k0 = c;                // key block start
    char* dst = Vw + (size_t)b * TILE_BYTES;
    short8 t0, t1;
    #pragma unroll
    for (int j = 0; j < 8; ++j) {
        t0[j] = (short)f2bf(tile[k0 + j][f]);
        t1[j] = (short)f2bf(tile[k0 + 8 + j][f]);
    }
    *(short8*)(dst + swz(f, k0 * 2)) = t0;
    *(short8*)(dst + swz(f, k0 * 2 + 16)) = t1;
}

// ---------------- main kernel (fast path) ----------------
__global__ __launch_bounds__(256, 4) void attn_v2(
    const float* __restrict__ Qg, const char* __restrict__ Kw,
    const char* __restrict__ Vw, float* __restrict__ Og)
{
    __shared__ short Ksm[2][KVBLK * HD];   // 2 x 8 KB
    __shared__ short Vsm[2][KVBLK * HD];   // 2 x 8 KB
    __shared__ short Psm[4 * 16 * KVBLK];  // 8 KB, wave-private quarters

    const int tid = threadIdx.x;
    const int w  = tid >> 6;
    const int l  = tid & 63;
    const int lg = l >> 4;
    const int ll = l & 15;

    // bijective XCD swizzle: 1536 blocks = 8 XCDs x 192, head-contiguous
    const int bid = blockIdx.x;
    const int work = (bid & 7) * (NHEADS * NQB / 8) + (bid >> 3);
    const int head = work / NQB;
    const int qb = work % NQB;
    const size_t hoff = (size_t)head * SEQ * HD;
    const int qbase = qb * QBLK + w * 16;

    // ---- Q fragments (A-layout: row=ll, k=lg*8+j+32*c), scale folded in
    short8 qf[2];
    {
        const float* qp = Qg + hoff + (size_t)(qbase + ll) * HD + lg * 8;
        #pragma unroll
        for (int c = 0; c < 2; ++c) {
            f32x4 a = *(const f32x4*)(qp + c * 32);
            f32x4 b = *(const f32x4*)(qp + c * 32 + 4);
            short8 t;
            #pragma unroll
            for (int j = 0; j < 4; ++j) {
                t[j]     = (short)f2bf(a[j] * 0.125f);
                t[j + 4] = (short)f2bf(b[j] * 0.125f);
            }
            qf[c] = t;
        }
    }

    float M[4], L[4];
    f32x4 o[4];
    const f32x4 zero = {0.f, 0.f, 0.f, 0.f};
    #pragma unroll
    for (int jj = 0; jj < 4; ++jj) { M[jj] = -1e30f; L[jj] = 0.f; }
    #pragma unroll
    for (int dt = 0; dt < 4; ++dt) o[dt] = zero;

    const char* const kbase = Kw + (size_t)head * NT * TILE_BYTES;
    const char* const vbase = Vw + (size_t)head * NT * TILE_BYTES;
    char* const Pb = (char*)Psm + w * (16 * KVBLK * 2);

    // async stage: wave 0/1 -> K halves, wave 2/3 -> V halves (4 KB each)
    auto stage = [&](int buf, int t) {
        const char* gsrc = ((w < 2) ? kbase : vbase) + (size_t)t * TILE_BYTES
                           + (w & 1) * 4096 + l * 16;
        char* lbase = (char*)((w < 2) ? Ksm[buf] : Vsm[buf]) + (w & 1) * 4096;
        #pragma unroll
        for (int j = 0; j < 4; ++j) {
            __builtin_amdgcn_global_load_lds(
                (const __attribute__((address_space(1))) void*)(gsrc + j * 1024),
                (__attribute__((address_space(3))) void*)(lbase + j * 1024),
                16, 0, 0);
        }
    };

    stage(0, 0);
    int cur = 0;

    for (int t = 0; t < NT; ++t) {
        __syncthreads();                       // buf[cur] ready; cur^1 free
        if (t + 1 < NT) stage(cur ^ 1, t + 1); // async prefetch under compute
        const char* Kb = (const char*)Ksm[cur];
        const char* Vb = (const char*)Vsm[cur];

        // ---- QK^T: S[16 q][64 keys] in 4 col-tiles
        f32x4 sc[4];
        #pragma unroll
        for (int ct = 0; ct < 4; ++ct) {
            f32x4 acc = zero;
            #pragma unroll
            for (int c = 0; c < 2; ++c) {
                short8 kb = *(const short8*)(Kb + swz(ct * 16 + ll, (c * 32 + lg * 8) * 2));
                acc = __builtin_amdgcn_mfma_f32_16x16x32_bf16(
                    __builtin_bit_cast(bf16x8, qf[c]),
                    __builtin_bit_cast(bf16x8, kb), acc, 0, 0, 0);
            }
            sc[ct] = acc;
        }

        // ---- online softmax; row jj shared by 16 lanes with same lg
        #pragma unroll
        for (int jj = 0; jj < 4; ++jj) {
            float m = fmaxf(fmaxf(sc[0][jj], sc[1][jj]), fmaxf(sc[2][jj], sc[3][jj]));
            m = fmaxf(m, __shfl_xor(m, 1));
            m = fmaxf(m, __shfl_xor(m, 2));
            m = fmaxf(m, __shfl_xor(m, 4));
            m = fmaxf(m, __shfl_xor(m, 8));
            const float mn = fmaxf(M[jj], m);
            const float corr = __expf(M[jj] - mn);
            M[jj] = mn;
            float p0 = __expf(sc[0][jj] - mn);
            float p1 = __expf(sc[1][jj] - mn);
            float p2 = __expf(sc[2][jj] - mn);
            float p3 = __expf(sc[3][jj] - mn);
            sc[0][jj] = p0; sc[1][jj] = p1; sc[2][jj] = p2; sc[3][jj] = p3;
            float s = (p0 + p1) + (p2 + p3);
            s += __shfl_xor(s, 1);
            s += __shfl_xor(s, 2);
            s += __shfl_xor(s, 4);
            s += __shfl_xor(s, 8);
            L[jj] = L[jj] * corr + s;
            #pragma unroll
            for (int dt = 0; dt < 4; ++dt) o[dt][jj] *= corr;
        }

        // ---- P: D-layout regs -> wave-private LDS [q][key] (bf16)
        #pragma unroll
        for (int ct = 0; ct < 4; ++ct) {
            #pragma unroll
            for (int jj = 0; jj < 4; ++jj) {
                *(short*)(Pb + swz(lg * 4 + jj, (ct * 16 + ll) * 2)) =
                    (short)f2bf(sc[ct][jj]);
            }
        }

        // ---- PV: O += P(16x64) * V(64x64)
        #pragma unroll
        for (int kc = 0; kc < 2; ++kc) {
            short8 pa = *(const short8*)(Pb + swz(ll, (kc * 32 + lg * 8) * 2));
            #pragma unroll
            for (int dt = 0; dt < 4; ++dt) {
                short8 vbf = *(const short8*)(Vb + swz(dt * 16 + ll, (kc * 32 + lg * 8) * 2));
                o[dt] = __builtin_amdgcn_mfma_f32_16x16x32_bf16(
                    __builtin_bit_cast(bf16x8, pa),
                    __builtin_bit_cast(bf16x8, vbf), o[dt], 0, 0, 0);
            }
        }
        cur ^= 1;
    }

    // ---- epilogue
    float* op = Og + hoff;
    #pragma unroll
    for (int jj = 0; jj < 4; ++jj) {
        const float inv = 1.0f / L[jj];
        const int q = qbase + lg * 4 + jj;
        #pragma unroll
        for (int dt = 0; dt < 4; ++dt)
            op[(size_t)q * HD + dt * 16 + ll] = o[dt][jj] * inv;
    }
}

// ---------------- fallback (round-1 kernel, used if ws too small) ----------------
__global__ __launch_bounds__(256, 4) void attn_v1(
    const float* __restrict__ Qg, const float* __restrict__ Kg,
    const float* __restrict__ Vg, float* __restrict__ Og)
{
    __shared__ short Ksm[KVBLK * HD];
    __shared__ short Vsm[HD * KVBLK];
    __shared__ short Psm[4 * 16 * KVBLK];

    const int tid = threadIdx.x;
    const int w  = tid >> 6;
    const int l  = tid & 63;
    const int lg = l >> 4;
    const int ll = l & 15;

    const int head = blockIdx.y;
    const size_t hoff = (size_t)head * SEQ * HD;
    const int qbase = blockIdx.x * QBLK + w * 16;

    short8 qf[2];
    {
        const float* qp = Qg + hoff + (size_t)(qbase + ll) * HD + lg * 8;
        #pragma unroll
        for (int c = 0; c < 2; ++c) {
            f32x4 a = *(const f32x4*)(qp + c * 32);
            f32x4 b = *(const f32x4*)(qp + c * 32 + 4);
            short8 t;
            #pragma unroll
            for (int j = 0; j < 4; ++j) {
                t[j]     = (short)f2bf(a[j] * 0.125f);
                t[j + 4] = (short)f2bf(b[j] * 0.125f);
            }
            qf[c] = t;
        }
    }

    float M[4], L[4];
    f32x4 o[4];
    const f32x4 zero = {0.f, 0.f, 0.f, 0.f};
    #pragma unroll
    for (int jj = 0; jj < 4; ++jj) { M[jj] = -1e30f; L[jj] = 0.f; }
    #pragma unroll
    for (int dt = 0; dt < 4; ++dt) o[dt] = zero;

    const int r0 = tid >> 3;
    const int c0 = (tid & 7) * 8;
    char* const Kb = (char*)Ksm;
    char* const Vb = (char*)Vsm;
    char* const Pb = (char*)Psm + w * (16 * KVBLK * 2);

    for (int t = 0; t < NT; ++t) {
        const int kv0 = t * KVBLK;
        __syncthreads();
        #pragma unroll
        for (int half = 0; half < 2; ++half) {
            const int r = r0 + half * 32;
            const float* kp = Kg + hoff + (size_t)(kv0 + r) * HD + c0;
            f32x4 a = *(const f32x4*)kp;
            f32x4 b = *(const f32x4*)(kp + 4);
            short8 kv;
            #pragma unroll
            for (int j = 0; j < 4; ++j) {
                kv[j]     = (short)f2bf(a[j]);
                kv[j + 4] = (short)f2bf(b[j]);
            }
            *(short8*)(Kb + swz(r, c0 * 2)) = kv;

            const float* vp = Vg + hoff + (size_t)(kv0 + r) * HD + c0;
            f32x4 va = *(const f32x4*)vp;
            f32x4 vb2 = *(const f32x4*)(vp + 4);
            #pragma unroll
            for (int j = 0; j < 4; ++j) {
                *(short*)(Vb + swz(c0 + j,     r * 2)) = (short)f2bf(va[j]);
                *(short*)(Vb + swz(c0 + 4 + j, r * 2)) = (short)f2bf(vb2[j]);
            }
        }
        __syncthreads();

        f32x4 sc[4];
        #pragma unroll
        for (int ct = 0; ct < 4; ++ct) {
            f32x4 acc = zero;
            #pragma unroll
            for (int c = 0; c < 2; ++c) {
                short8 kb = *(const short8*)(Kb + swz(ct * 16 + ll, (c * 32 + lg * 8) * 2));
                acc = __builtin_amdgcn_mfma_f32_16x16x32_bf16(
                    __builtin_bit_cast(bf16x8, qf[c]),
                    __builtin_bit_cast(bf16x8, kb), acc, 0, 0, 0);
            }
            sc[ct] = acc;
        }

        #pragma unroll
        for (int jj = 0; jj < 4; ++jj) {
            float m = fmaxf(fmaxf(sc[0][jj], sc[1][jj]), fmaxf(sc[2][jj], sc[3][jj]));
            m = fmaxf(m, __shfl_xor(m, 1));
            m = fmaxf(m, __shfl_xor(m, 2));
            m = fmaxf(m, __shfl_xor(m, 4));
            m = fmaxf(m, __shfl_xor(m, 8));
            const float mn = fmaxf(M[jj], m);
            const float corr = __expf(M[jj] - mn);
            M[jj] = mn;
            float p0 = __expf(sc[0][jj] - mn);
            float p1 = __expf(sc[1][jj] - mn);
            float p2 = __expf(sc[2][jj] - mn);
            float p3 = __expf(sc[3][jj] - mn);
            sc[0][jj] = p0; sc[1][jj] = p1; sc[2][jj] = p2; sc[3][jj] = p3;
            float s = (p0 + p1) + (p2 + p3);
            s += __shfl_xor(s, 1);
            s += __shfl_xor(s, 2);
            s += __shfl_xor(s, 4);
            s += __shfl_xor(s, 8);
            L[jj] = L[jj] * corr + s;
            #pragma unroll
            for (int dt = 0; dt < 4; ++dt) o[dt][jj] *= corr;
        }

        #pragma unroll
        for (int ct = 0; ct < 4; ++ct) {
            #pragma unroll
            for (int jj = 0; jj < 4; ++jj) {
                *(short*)(Pb + swz(lg * 4 + jj, (ct * 16 + ll) * 2)) =
                    (short)f2bf(sc[ct][jj]);
            }
        }

        #pragma unroll
        for (int kc = 0; kc < 2; ++kc) {
            short8 pa = *(const short8*)(Pb + swz(ll, (kc * 32 + lg * 8) * 2));
            #pragma unroll
            for (int dt = 0; dt < 4; ++dt) {
                short8 vbf = *(const short8*)(Vb + swz(dt * 16 + ll, (kc * 32 + lg * 8) * 2));
                o[dt] = __builtin_amdgcn_mfma_f32_16x16x32_bf16(
                    __builtin_bit_cast(bf16x8, pa),
                    __builtin_bit_cast(bf16x8, vbf), o[dt], 0, 0, 0);
            }
        }
    }

    float* op = Og + hoff;
    #pragma unroll
    for (int jj = 0; jj < 4; ++jj) {
        const float inv = 1.0f / L[jj];
        const int q = qbase + lg * 4 + jj;
        #pragma unroll
        for (int dt = 0; dt < 4; ++dt)
            op[(size_t)q * HD + dt * 16 + ll] = o[dt][jj] * inv;
    }
}

extern "C" void kernel_launch(void* const* d_in, const int* in_sizes, int n_in,
                              void* d_out, int out_size, void* d_ws, size_t ws_size,
                              hipStream_t stream) {
    const float* Q = (const float*)d_in[0];
    const float* K = (const float*)d_in[1];
    const float* V = (const float*)d_in[2];
    float* O = (float*)d_out;

    if (ws_size >= WS_NEEDED) {
        char* Kw = (char*)d_ws;
        char* Vw = Kw + (size_t)NHEADS * SEQ * HD * 2;
        conv_k<<<NHEADS * SEQ * HD / (8 * 256), 256, 0, stream>>>(K, Kw);
        conv_vt<<<NHEADS * NT, 256, 0, stream>>>(V, Vw);
        attn_v2<<<NHEADS * NQB, 256, 0, stream>>>(Q, Kw, Vw, O);
    } else {
        dim3 grid(NQB, NHEADS);
        attn_v1<<<grid, 256, 0, stream>>>(Q, K, V, O);
    }
}

// Round 3
// 196.831 us; speedup vs baseline: 2.7847x; 1.6741x over previous
//
#include <hip/hip_runtime.h>

// Flash attention fwd, B=2 H=12 S=4096 D=64, fp32 in/out, bf16 MFMA compute.
// Round 3: swapped QK^T (mfma(K,Q) -> S^T) so each lane owns one q-row:
// softmax reductions go in-register (15 ops + 2 shfl vs 32 shfl), P packs
// to ds_write_b64, PV swapped (O^T) so rescale needs no broadcast, epilogue
// stores f32x4. K/V pre-converted to bf16 swizzled tiles in d_ws;
// global_load_lds(16B) staging, double-buffered.

typedef float f32x4 __attribute__((ext_vector_type(4)));
typedef short short8 __attribute__((ext_vector_type(8)));
typedef __bf16 bf16x8 __attribute__((ext_vector_type(8)));
typedef __bf16 bf16x4 __attribute__((ext_vector_type(4)));

#define NB 2
#define NH 12
#define NHEADS (NB * NH)
#define SEQ 4096
#define HD 64
#define QBLK 64
#define KVBLK 64
#define NT (SEQ / KVBLK)
#define NQB (SEQ / QBLK)
#define TILE_BYTES (KVBLK * HD * 2)            // 8192 B per bf16 tile
#define WS_NEEDED ((size_t)NHEADS * SEQ * HD * 2 * 2)

__device__ __forceinline__ unsigned short f2bf(float x) {
    unsigned u = __builtin_bit_cast(unsigned, x);
    u += 0x7fffu + ((u >> 16) & 1u);   // round-to-nearest-even
    return (unsigned short)(u >> 16);
}

// byte offset into a row-major [R][64] bf16 tile (128B rows), bank-swizzled
__device__ __forceinline__ int swz(int row, int colByte) {
    return row * 128 + (colByte ^ ((row & 7) << 4));
}

// ---------------- pre-pass: K -> bf16 swizzled tiles ----------------
__global__ __launch_bounds__(256) void conv_k(const float* __restrict__ Kg,
                                              char* __restrict__ Kw) {
    const int g = blockIdx.x * 256 + threadIdx.x;   // one 8-element block
    const int e0 = g * 8;
    const int head = e0 >> 18;                      // SEQ*HD = 262144
    const int rem = e0 & (262144 - 1);
    const int row = rem >> 6;
    const int col = rem & 63;
    const int tile = row >> 6;
    const int r = row & 63;
    f32x4 a = *(const f32x4*)(Kg + (size_t)e0);
    f32x4 b = *(const f32x4*)(Kg + (size_t)e0 + 4);
    short8 t;
    #pragma unroll
    for (int j = 0; j < 4; ++j) {
        t[j]     = (short)f2bf(a[j]);
        t[j + 4] = (short)f2bf(b[j]);
    }
    *(short8*)(Kw + ((size_t)head * NT + tile) * TILE_BYTES + swz(r, col * 2)) = t;
}

// ---------- pre-pass: V -> V^T bf16 swizzled tiles (via LDS) ----------
__global__ __launch_bounds__(256) void conv_vt(const float* __restrict__ Vg,
                                               char* __restrict__ Vw) {
    __shared__ float tile[64][65];   // +1 pad: conflict-free column reads
    const int b = blockIdx.x;        // head * NT + t
    const int tid = threadIdx.x;
    const float* src = Vg + (size_t)b * (KVBLK * HD);
    const int r = tid >> 2;
    const int c = (tid & 3) * 16;
    f32x4 v[4];
    #pragma unroll
    for (int j = 0; j < 4; ++j) v[j] = *(const f32x4*)(src + r * 64 + c + j * 4);
    #pragma unroll
    for (int j = 0; j < 16; ++j) tile[r][c + j] = v[j >> 2][j & 3];
    __syncthreads();
    const int f = r;                 // output feature row
    const int k0 = c;                // key block start
    char* dst = Vw + (size_t)b * TILE_BYTES;
    short8 t0, t1;
    #pragma unroll
    for (int j = 0; j < 8; ++j) {
        t0[j] = (short)f2bf(tile[k0 + j][f]);
        t1[j] = (short)f2bf(tile[k0 + 8 + j][f]);
    }
    *(short8*)(dst + swz(f, k0 * 2)) = t0;
    *(short8*)(dst + swz(f, k0 * 2 + 16)) = t1;
}

// ---------------- main kernel ----------------
__global__ __launch_bounds__(256, 4) void attn_v3(
    const float* __restrict__ Qg, const char* __restrict__ Kw,
    const char* __restrict__ Vw, float* __restrict__ Og)
{
    __shared__ short Ksm[2][KVBLK * HD];   // 2 x 8 KB
    __shared__ short Vsm[2][KVBLK * HD];   // 2 x 8 KB
    __shared__ short Psm[4 * 16 * KVBLK];  // 8 KB, wave-private quarters

    const int tid = threadIdx.x;
    const int w  = tid >> 6;
    const int l  = tid & 63;
    const int lg = l >> 4;
    const int ll = l & 15;

    // bijective XCD swizzle: 1536 blocks = 8 XCDs x 192, head-contiguous
    const int bid = blockIdx.x;
    const int work = (bid & 7) * (NHEADS * NQB / 8) + (bid >> 3);
    const int head = work / NQB;
    const int qb = work % NQB;
    const size_t hoff = (size_t)head * SEQ * HD;
    const int qbase = qb * QBLK + w * 16;

    // ---- Q fragments (B-layout: col=q=ll, k=d=lg*8+j+32*c), scale folded in
    short8 qf[2];
    {
        const float* qp = Qg + hoff + (size_t)(qbase + ll) * HD + lg * 8;
        #pragma unroll
        for (int c = 0; c < 2; ++c) {
            f32x4 a = *(const f32x4*)(qp + c * 32);
            f32x4 b = *(const f32x4*)(qp + c * 32 + 4);
            short8 t;
            #pragma unroll
            for (int j = 0; j < 4; ++j) {
                t[j]     = (short)f2bf(a[j] * 0.125f);
                t[j + 4] = (short)f2bf(b[j] * 0.125f);
            }
            qf[c] = t;
        }
    }

    // per-lane softmax state for q = qbase + ll (replicated across lg)
    float M = -1e30f, L = 0.f;
    f32x4 o[4];   // O^T: o[dt][jj] = O[q=ll][d=dt*16+lg*4+jj]
    const f32x4 zero = {0.f, 0.f, 0.f, 0.f};
    #pragma unroll
    for (int dt = 0; dt < 4; ++dt) o[dt] = zero;

    const char* const kbase = Kw + (size_t)head * NT * TILE_BYTES;
    const char* const vbase = Vw + (size_t)head * NT * TILE_BYTES;
    char* const Pb = (char*)Psm + w * (16 * KVBLK * 2);

    // async stage: wave 0/1 -> K halves, wave 2/3 -> V halves (4 KB each)
    auto stage = [&](int buf, int t) {
        const char* gsrc = ((w < 2) ? kbase : vbase) + (size_t)t * TILE_BYTES
                           + (w & 1) * 4096 + l * 16;
        char* lbase = (char*)((w < 2) ? Ksm[buf] : Vsm[buf]) + (w & 1) * 4096;
        #pragma unroll
        for (int j = 0; j < 4; ++j) {
            __builtin_amdgcn_global_load_lds(
                (const __attribute__((address_space(1))) void*)(gsrc + j * 1024),
                (__attribute__((address_space(3))) void*)(lbase + j * 1024),
                16, 0, 0);
        }
    };

    stage(0, 0);
    int cur = 0;

    for (int t = 0; t < NT; ++t) {
        __syncthreads();                       // buf[cur] ready; cur^1 free
        if (t + 1 < NT) stage(cur ^ 1, t + 1); // async prefetch under compute
        const char* Kb = (const char*)Ksm[cur];
        const char* Vb = (const char*)Vsm[cur];

        // ---- swapped QK^T: S^T[key][q]; lane holds keys ct*16+lg*4+jj, q=ll
        f32x4 sc[4];
        #pragma unroll
        for (int ct = 0; ct < 4; ++ct) {
            f32x4 acc = zero;
            #pragma unroll
            for (int c = 0; c < 2; ++c) {
                short8 kb = *(const short8*)(Kb + swz(ct * 16 + ll, c * 64 + lg * 16));
                acc = __builtin_amdgcn_mfma_f32_16x16x32_bf16(
                    __builtin_bit_cast(bf16x8, kb),      // A = K (keys x d)
                    __builtin_bit_cast(bf16x8, qf[c]),   // B = Q^T (d x q)
                    acc, 0, 0, 0);
            }
            sc[ct] = acc;
        }

        // ---- online softmax, row = q = ll, fully per-lane + 2 shfl
        float m01 = fmaxf(fmaxf(sc[0][0], sc[0][1]), fmaxf(sc[0][2], sc[0][3]));
        float m11 = fmaxf(fmaxf(sc[1][0], sc[1][1]), fmaxf(sc[1][2], sc[1][3]));
        float m21 = fmaxf(fmaxf(sc[2][0], sc[2][1]), fmaxf(sc[2][2], sc[2][3]));
        float m31 = fmaxf(fmaxf(sc[3][0], sc[3][1]), fmaxf(sc[3][2], sc[3][3]));
        float pm = fmaxf(fmaxf(m01, m11), fmaxf(m21, m31));
        pm = fmaxf(pm, __shfl_xor(pm, 16));
        pm = fmaxf(pm, __shfl_xor(pm, 32));
        const float mn = fmaxf(M, pm);
        const float corr = __expf(M - mn);
        M = mn;
        #pragma unroll
        for (int ct = 0; ct < 4; ++ct)
            #pragma unroll
            for (int jj = 0; jj < 4; ++jj)
                sc[ct][jj] = __expf(sc[ct][jj] - mn);
        float s0 = (sc[0][0] + sc[0][1]) + (sc[0][2] + sc[0][3]);
        float s1 = (sc[1][0] + sc[1][1]) + (sc[1][2] + sc[1][3]);
        float s2 = (sc[2][0] + sc[2][1]) + (sc[2][2] + sc[2][3]);
        float s3 = (sc[3][0] + sc[3][1]) + (sc[3][2] + sc[3][3]);
        float s = (s0 + s1) + (s2 + s3);
        s += __shfl_xor(s, 16);
        s += __shfl_xor(s, 32);
        L = L * corr + s;
        #pragma unroll
        for (int dt = 0; dt < 4; ++dt) o[dt] *= corr;

        // ---- P^T pack: 4 consecutive keys -> one ds_write_b64 per ct
        // P-lds layout [q=ll][key], swizzled; key0 = ct*16+lg*4
        #pragma unroll
        for (int ct = 0; ct < 4; ++ct) {
            bf16x4 pk;
            #pragma unroll
            for (int jj = 0; jj < 4; ++jj) pk[jj] = (__bf16)sc[ct][jj];
            *(bf16x4*)(Pb + swz(ll, ct * 32 + lg * 8)) = pk;
        }

        // ---- PV swapped: O^T += V^T (d x keys) * P^T (keys x q)
        #pragma unroll
        for (int kc = 0; kc < 2; ++kc) {
            short8 pb = *(const short8*)(Pb + swz(ll, kc * 64 + lg * 16));
            #pragma unroll
            for (int dt = 0; dt < 4; ++dt) {
                short8 va = *(const short8*)(Vb + swz(dt * 16 + ll, kc * 64 + lg * 16));
                o[dt] = __builtin_amdgcn_mfma_f32_16x16x32_bf16(
                    __builtin_bit_cast(bf16x8, va),      // A = V^T
                    __builtin_bit_cast(bf16x8, pb),      // B = P^T
                    o[dt], 0, 0, 0);
            }
        }
        cur ^= 1;
    }

    // ---- epilogue: O[q=ll][d=dt*16+lg*4+jj], f32x4 stores
    const float inv = 1.0f / L;
    float* op = Og + hoff + (size_t)(qbase + ll) * HD;
    #pragma unroll
    for (int dt = 0; dt < 4; ++dt) {
        f32x4 v = o[dt];
        v *= inv;
        *(f32x4*)(op + dt * 16 + lg * 4) = v;
    }
}

// ---------------- fallback (round-1 kernel, used if ws too small) ----------------
__global__ __launch_bounds__(256, 4) void attn_v1(
    const float* __restrict__ Qg, const float* __restrict__ Kg,
    const float* __restrict__ Vg, float* __restrict__ Og)
{
    __shared__ short Ksm[KVBLK * HD];
    __shared__ short Vsm[HD * KVBLK];
    __shared__ short Psm[4 * 16 * KVBLK];

    const int tid = threadIdx.x;
    const int w  = tid >> 6;
    const int l  = tid & 63;
    const int lg = l >> 4;
    const int ll = l & 15;

    const int head = blockIdx.y;
    const size_t hoff = (size_t)head * SEQ * HD;
    const int qbase = blockIdx.x * QBLK + w * 16;

    short8 qf[2];
    {
        const float* qp = Qg + hoff + (size_t)(qbase + ll) * HD + lg * 8;
        #pragma unroll
        for (int c = 0; c < 2; ++c) {
            f32x4 a = *(const f32x4*)(qp + c * 32);
            f32x4 b = *(const f32x4*)(qp + c * 32 + 4);
            short8 t;
            #pragma unroll
            for (int j = 0; j < 4; ++j) {
                t[j]     = (short)f2bf(a[j] * 0.125f);
                t[j + 4] = (short)f2bf(b[j] * 0.125f);
            }
            qf[c] = t;
        }
    }

    float M[4], L[4];
    f32x4 o[4];
    const f32x4 zero = {0.f, 0.f, 0.f, 0.f};
    #pragma unroll
    for (int jj = 0; jj < 4; ++jj) { M[jj] = -1e30f; L[jj] = 0.f; }
    #pragma unroll
    for (int dt = 0; dt < 4; ++dt) o[dt] = zero;

    const int r0 = tid >> 3;
    const int c0 = (tid & 7) * 8;
    char* const Kb = (char*)Ksm;
    char* const Vb = (char*)Vsm;
    char* const Pb = (char*)Psm + w * (16 * KVBLK * 2);

    for (int t = 0; t < NT; ++t) {
        const int kv0 = t * KVBLK;
        __syncthreads();
        #pragma unroll
        for (int half = 0; half < 2; ++half) {
            const int r = r0 + half * 32;
            const float* kp = Kg + hoff + (size_t)(kv0 + r) * HD + c0;
            f32x4 a = *(const f32x4*)kp;
            f32x4 b = *(const f32x4*)(kp + 4);
            short8 kv;
            #pragma unroll
            for (int j = 0; j < 4; ++j) {
                kv[j]     = (short)f2bf(a[j]);
                kv[j + 4] = (short)f2bf(b[j]);
            }
            *(short8*)(Kb + swz(r, c0 * 2)) = kv;

            const float* vp = Vg + hoff + (size_t)(kv0 + r) * HD + c0;
            f32x4 va = *(const f32x4*)vp;
            f32x4 vb2 = *(const f32x4*)(vp + 4);
            #pragma unroll
            for (int j = 0; j < 4; ++j) {
                *(short*)(Vb + swz(c0 + j,     r * 2)) = (short)f2bf(va[j]);
                *(short*)(Vb + swz(c0 + 4 + j, r * 2)) = (short)f2bf(vb2[j]);
            }
        }
        __syncthreads();

        f32x4 sc[4];
        #pragma unroll
        for (int ct = 0; ct < 4; ++ct) {
            f32x4 acc = zero;
            #pragma unroll
            for (int c = 0; c < 2; ++c) {
                short8 kb = *(const short8*)(Kb + swz(ct * 16 + ll, (c * 32 + lg * 8) * 2));
                acc = __builtin_amdgcn_mfma_f32_16x16x32_bf16(
                    __builtin_bit_cast(bf16x8, qf[c]),
                    __builtin_bit_cast(bf16x8, kb), acc, 0, 0, 0);
            }
            sc[ct] = acc;
        }

        #pragma unroll
        for (int jj = 0; jj < 4; ++jj) {
            float m = fmaxf(fmaxf(sc[0][jj], sc[1][jj]), fmaxf(sc[2][jj], sc[3][jj]));
            m = fmaxf(m, __shfl_xor(m, 1));
            m = fmaxf(m, __shfl_xor(m, 2));
            m = fmaxf(m, __shfl_xor(m, 4));
            m = fmaxf(m, __shfl_xor(m, 8));
            const float mn = fmaxf(M[jj], m);
            const float corr = __expf(M[jj] - mn);
            M[jj] = mn;
            float p0 = __expf(sc[0][jj] - mn);
            float p1 = __expf(sc[1][jj] - mn);
            float p2 = __expf(sc[2][jj] - mn);
            float p3 = __expf(sc[3][jj] - mn);
            sc[0][jj] = p0; sc[1][jj] = p1; sc[2][jj] = p2; sc[3][jj] = p3;
            float s = (p0 + p1) + (p2 + p3);
            s += __shfl_xor(s, 1);
            s += __shfl_xor(s, 2);
            s += __shfl_xor(s, 4);
            s += __shfl_xor(s, 8);
            L[jj] = L[jj] * corr + s;
            #pragma unroll
            for (int dt = 0; dt < 4; ++dt) o[dt][jj] *= corr;
        }

        #pragma unroll
        for (int ct = 0; ct < 4; ++ct) {
            #pragma unroll
            for (int jj = 0; jj < 4; ++jj) {
                *(short*)(Pb + swz(lg * 4 + jj, (ct * 16 + ll) * 2)) =
                    (short)f2bf(sc[ct][jj]);
            }
        }

        #pragma unroll
        for (int kc = 0; kc < 2; ++kc) {
            short8 pa = *(const short8*)(Pb + swz(ll, (kc * 32 + lg * 8) * 2));
            #pragma unroll
            for (int dt = 0; dt < 4; ++dt) {
                short8 vbf = *(const short8*)(Vb + swz(dt * 16 + ll, (kc * 32 + lg * 8) * 2));
                o[dt] = __builtin_amdgcn_mfma_f32_16x16x32_bf16(
                    __builtin_bit_cast(bf16x8, pa),
                    __builtin_bit_cast(bf16x8, vbf), o[dt], 0, 0, 0);
            }
        }
    }

    float* op = Og + hoff;
    #pragma unroll
    for (int jj = 0; jj < 4; ++jj) {
        const float inv = 1.0f / L[jj];
        const int q = qbase + lg * 4 + jj;
        #pragma unroll
        for (int dt = 0; dt < 4; ++dt)
            op[(size_t)q * HD + dt * 16 + ll] = o[dt][jj] * inv;
    }
}

extern "C" void kernel_launch(void* const* d_in, const int* in_sizes, int n_in,
                              void* d_out, int out_size, void* d_ws, size_t ws_size,
                              hipStream_t stream) {
    const float* Q = (const float*)d_in[0];
    const float* K = (const float*)d_in[1];
    const float* V = (const float*)d_in[2];
    float* O = (float*)d_out;

    if (ws_size >= WS_NEEDED) {
        char* Kw = (char*)d_ws;
        char* Vw = Kw + (size_t)NHEADS * SEQ * HD * 2;
        conv_k<<<NHEADS * SEQ * HD / (8 * 256), 256, 0, stream>>>(K, Kw);
        conv_vt<<<NHEADS * NT, 256, 0, stream>>>(V, Vw);
        attn_v3<<<NHEADS * NQB, 256, 0, stream>>>(Q, Kw, Vw, O);
    } else {
        dim3 grid(NQB, NHEADS);
        attn_v1<<<grid, 256, 0, stream>>>(Q, K, V, O);
    }
}